// Round 1
// baseline (309.337 us; speedup 1.0000x reference)
//
#include <hip/hip_runtime.h>
#include <math.h>

#define N_NODES 8192
#define N_EDGES 262144
#define NFEAT 128
#define NHID 256
#define NCLASS 16

// ---------------- degree accumulation ----------------
__global__ void deg_kernel(const int* __restrict__ ei, const float* __restrict__ ew,
                           float* __restrict__ deg, int E) {
    int e = blockIdx.x * blockDim.x + threadIdx.x;
    if (e < E) atomicAdd(&deg[ei[e]], ew[e]);
}

__global__ void dinv_kernel(const float* __restrict__ deg, float* __restrict__ dinv, int n) {
    int i = blockIdx.x * blockDim.x + threadIdx.x;
    if (i < n) {
        float d = deg[i] + 1.0f;  // + self loop
        dinv[i] = (d > 0.0f) ? (1.0f / sqrtf(d)) : 0.0f;
    }
}

// ---------------- V1 = dinv * (x @ W1);  Hpre = V1 (self-loop init) ----------------
__global__ __launch_bounds__(256) void xw1_kernel(const float* __restrict__ x,
                                                  const float* __restrict__ W1,
                                                  const float* __restrict__ dinv,
                                                  float* __restrict__ V1,
                                                  float* __restrict__ Hpre) {
    __shared__ float xs[NFEAT];
    int row = blockIdx.x;
    int j = threadIdx.x;             // 0..255 output column
    if (j < NFEAT) xs[j] = x[row * NFEAT + j];
    __syncthreads();
    float acc = 0.0f;
    #pragma unroll 8
    for (int k = 0; k < NFEAT; ++k) acc += xs[k] * W1[k * NHID + j];
    float v = dinv[row] * acc;
    V1[row * NHID + j] = v;
    Hpre[row * NHID + j] = v;
}

// ---------------- Hpre[r] += w * V1[c] (one block per edge) ----------------
__global__ __launch_bounds__(256) void spmm1_kernel(const int* __restrict__ ei,
                                                    const float* __restrict__ ew,
                                                    const float* __restrict__ V1,
                                                    float* __restrict__ Hpre, int E) {
    int e = blockIdx.x;
    int j = threadIdx.x;
    int r = ei[e];
    int c = ei[E + e];
    float w = ew[e];
    atomicAdd(&Hpre[r * NHID + j], w * V1[c * NHID + j]);
}

// ---------------- H = relu(dinv*Hpre + b1) ----------------
__global__ void h_kernel(const float* __restrict__ Hpre, const float* __restrict__ dinv,
                         const float* __restrict__ b1, float* __restrict__ H) {
    int idx = blockIdx.x * blockDim.x + threadIdx.x;  // N*NHID total
    int row = idx >> 8;   // /256
    int j = idx & 255;
    float v = dinv[row] * Hpre[idx] + b1[j];
    H[idx] = v > 0.0f ? v : 0.0f;
}

// ---------------- V2 = dinv * (H @ W2); outpre = V2 ----------------
__global__ __launch_bounds__(256) void hw2_kernel(const float* __restrict__ H,
                                                  const float* __restrict__ W2,
                                                  const float* __restrict__ dinv,
                                                  float* __restrict__ V2,
                                                  float* __restrict__ outpre) {
    __shared__ float w2s[NHID * NCLASS];  // 16 KB
    int t = threadIdx.x;
    #pragma unroll
    for (int i = 0; i < 16; ++i) w2s[i * 256 + t] = W2[i * 256 + t];
    __syncthreads();
    int rr = t >> 4;          // 0..15 row within block
    int j = t & 15;           // class
    int row = blockIdx.x * 16 + rr;
    float acc = 0.0f;
    #pragma unroll 8
    for (int k = 0; k < NHID; ++k) acc += H[row * NHID + k] * w2s[k * NCLASS + j];
    float v = dinv[row] * acc;
    V2[row * NCLASS + j] = v;
    outpre[row * NCLASS + j] = v;
}

// ---------------- outpre[r] += w * V2[c] (16 threads per edge) ----------------
__global__ __launch_bounds__(256) void spmm2_kernel(const int* __restrict__ ei,
                                                    const float* __restrict__ ew,
                                                    const float* __restrict__ V2,
                                                    float* __restrict__ outpre, int E) {
    int idx = blockIdx.x * blockDim.x + threadIdx.x;
    int e = idx >> 4;
    int j = idx & 15;
    if (e < E) {
        int r = ei[e];
        int c = ei[E + e];
        atomicAdd(&outpre[r * NCLASS + j], ew[e] * V2[c * NCLASS + j]);
    }
}

// ---------------- logits = dinv*outpre + b2 -> log_softmax ----------------
__global__ void final_kernel(const float* __restrict__ outpre, const float* __restrict__ dinv,
                             const float* __restrict__ b2, float* __restrict__ out, int n) {
    int row = blockIdx.x * blockDim.x + threadIdx.x;
    if (row < n) {
        float v[NCLASS];
        float di = dinv[row];
        float mx = -INFINITY;
        #pragma unroll
        for (int j = 0; j < NCLASS; ++j) {
            v[j] = di * outpre[row * NCLASS + j] + b2[j];
            mx = fmaxf(mx, v[j]);
        }
        float s = 0.0f;
        #pragma unroll
        for (int j = 0; j < NCLASS; ++j) s += expf(v[j] - mx);
        float lse = mx + logf(s);
        #pragma unroll
        for (int j = 0; j < NCLASS; ++j) out[row * NCLASS + j] = v[j] - lse;
    }
}

extern "C" void kernel_launch(void* const* d_in, const int* in_sizes, int n_in,
                              void* d_out, int out_size, void* d_ws, size_t ws_size,
                              hipStream_t stream) {
    const float* x  = (const float*)d_in[0];
    const int*   ei = (const int*)d_in[1];      // [2, E] flat: row = ei[e], col = ei[E+e]
    const float* ew = (const float*)d_in[2];
    const float* W1 = (const float*)d_in[3];
    const float* b1 = (const float*)d_in[4];
    const float* W2 = (const float*)d_in[5];
    const float* b2 = (const float*)d_in[6];
    float* out = (float*)d_out;

    const int E = N_EDGES;
    const int n = N_NODES;

    // workspace carve-up (bytes)
    char* ws = (char*)d_ws;
    float* deg    = (float*)(ws);                                  // 8192 f32
    float* dinv   = (float*)(ws + 32768);                          // 8192 f32
    float* V1     = (float*)(ws + 65536);                          // 8192*256 f32 = 8 MB
    float* Hpre   = (float*)(ws + 65536 + (size_t)8388608);        // 8 MB
    float* H      = (float*)(ws + 65536 + (size_t)2 * 8388608);    // 8 MB
    float* V2     = (float*)(ws + 65536 + (size_t)3 * 8388608);    // 512 KB
    float* outpre = (float*)(ws + 65536 + (size_t)3 * 8388608 + 524288);  // 512 KB

    // deg accumulates atomically -> must start at zero every call
    hipMemsetAsync(deg, 0, n * sizeof(float), stream);

    deg_kernel<<<(E + 255) / 256, 256, 0, stream>>>(ei, ew, deg, E);
    dinv_kernel<<<(n + 255) / 256, 256, 0, stream>>>(deg, dinv, n);

    xw1_kernel<<<n, 256, 0, stream>>>(x, W1, dinv, V1, Hpre);
    spmm1_kernel<<<E, 256, 0, stream>>>(ei, ew, V1, Hpre, E);
    h_kernel<<<(n * NHID) / 256, 256, 0, stream>>>(Hpre, dinv, b1, H);

    hw2_kernel<<<n / 16, 256, 0, stream>>>(H, W2, dinv, V2, outpre);
    spmm2_kernel<<<(E * NCLASS) / 256, 256, 0, stream>>>(ei, ew, V2, outpre, E);

    final_kernel<<<(n + 255) / 256, 256, 0, stream>>>(outpre, dinv, b2, out, n);
}

// Round 3
// 140.601 us; speedup vs baseline: 2.2001x; 2.2001x over previous
//
#include <hip/hip_runtime.h>
#include <math.h>

#define N_NODES 8192
#define N_EDGES 262144
#define NFEAT 128
#define NHID 256
#define NCLASS 16

// ---------------- histogram + weighted degree ----------------
__global__ void hist_deg_kernel(const int* __restrict__ ei, const float* __restrict__ ew,
                                float* __restrict__ deg, int* __restrict__ counts, int E) {
    int e = blockIdx.x * blockDim.x + threadIdx.x;
    if (e < E) {
        int r = ei[e];
        atomicAdd(&deg[r], ew[e]);
        atomicAdd(&counts[r], 1);
    }
}

__global__ void dinv_kernel(const float* __restrict__ deg, float* __restrict__ dinv, int n) {
    int i = blockIdx.x * blockDim.x + threadIdx.x;
    if (i < n) {
        float d = deg[i] + 1.0f;  // + self loop
        dinv[i] = (d > 0.0f) ? (1.0f / sqrtf(d)) : 0.0f;
    }
}

// ---------------- exclusive prefix scan of counts (single block) ----------------
__global__ __launch_bounds__(1024) void scan_kernel(const int* __restrict__ counts,
                                                    int* __restrict__ rowstart) {
    __shared__ int wsum[16];
    __shared__ int woff[16];
    int t = threadIdx.x;              // 0..1023, each handles 8 rows
    int base = t * 8;
    int vals[8];
    int s = 0;
    #pragma unroll
    for (int i = 0; i < 8; ++i) { vals[i] = s; s += counts[base + i]; }
    int lane = t & 63, wave = t >> 6;
    int sc = s;  // inclusive wave scan of per-thread totals
    #pragma unroll
    for (int off = 1; off < 64; off <<= 1) {
        int u = __shfl_up(sc, off);
        if (lane >= off) sc += u;
    }
    if (lane == 63) wsum[wave] = sc;
    __syncthreads();
    if (t == 0) { int acc = 0; for (int i = 0; i < 16; ++i) { woff[i] = acc; acc += wsum[i]; } }
    __syncthreads();
    int texcl = sc - s + woff[wave];
    #pragma unroll
    for (int i = 0; i < 8; ++i) rowstart[base + i] = texcl + vals[i];
    if (t == 1023) rowstart[N_NODES] = texcl + s;  // == E
}

// ---------------- scatter edges into CSR order ----------------
__global__ void scatter_kernel(const int* __restrict__ ei, const float* __restrict__ ew,
                               const int* __restrict__ rowstart, int* __restrict__ cur,
                               int* __restrict__ colbuf, float* __restrict__ wbuf, int E) {
    int e = blockIdx.x * blockDim.x + threadIdx.x;
    if (e < E) {
        int r = ei[e];
        int pos = rowstart[r] + atomicAdd(&cur[r], 1);
        colbuf[pos] = ei[E + e];
        wbuf[pos] = ew[e];
    }
}

// ---------------- V1 = dinv * (x @ W1) ----------------
__global__ __launch_bounds__(256) void xw1_kernel(const float* __restrict__ x,
                                                  const float* __restrict__ W1,
                                                  const float* __restrict__ dinv,
                                                  float* __restrict__ V1) {
    __shared__ float xs[NFEAT];
    int row = blockIdx.x;
    int j = threadIdx.x;
    if (j < NFEAT) xs[j] = x[row * NFEAT + j];
    __syncthreads();
    float acc = 0.0f;
    #pragma unroll 8
    for (int k = 0; k < NFEAT; ++k) acc += xs[k] * W1[k * NHID + j];
    V1[row * NHID + j] = dinv[row] * acc;
}

// ---------------- H[r] = relu(dinv[r]*(V1[r] + sum_e w*V1[c]) + b1)  (gather) ----------------
__global__ __launch_bounds__(256) void spmm1_csr(const int* __restrict__ rowstart,
                                                 const int* __restrict__ colbuf,
                                                 const float* __restrict__ wbuf,
                                                 const float* __restrict__ V1,
                                                 const float* __restrict__ dinv,
                                                 const float* __restrict__ b1,
                                                 float* __restrict__ H) {
    __shared__ int cS[256];
    __shared__ float wS[256];
    int r = blockIdx.x;
    int j = threadIdx.x;
    int s = rowstart[r], e = rowstart[r + 1];
    float acc = V1[r * NHID + j];  // self loop
    for (int base = s; base < e; base += 256) {
        int k = base + j;
        if (k < e) { cS[j] = colbuf[k]; wS[j] = wbuf[k]; }
        __syncthreads();
        int cnt = min(256, e - base);
        for (int t = 0; t < cnt; ++t)
            acc += wS[t] * V1[cS[t] * NHID + j];
        __syncthreads();
    }
    float v = dinv[r] * acc + b1[j];
    H[r * NHID + j] = v > 0.0f ? v : 0.0f;
}

// ---------------- V2 = dinv * (H @ W2) ----------------
__global__ __launch_bounds__(256) void hw2_kernel(const float* __restrict__ H,
                                                  const float* __restrict__ W2,
                                                  const float* __restrict__ dinv,
                                                  float* __restrict__ V2) {
    __shared__ float w2s[NHID * NCLASS];  // 16 KB
    int t = threadIdx.x;
    #pragma unroll
    for (int i = 0; i < 16; ++i) w2s[i * 256 + t] = W2[i * 256 + t];
    __syncthreads();
    int rr = t >> 4;
    int j = t & 15;
    int row = blockIdx.x * 16 + rr;
    float acc = 0.0f;
    #pragma unroll 8
    for (int k = 0; k < NHID; ++k) acc += H[row * NHID + k] * w2s[k * NCLASS + j];
    V2[row * NCLASS + j] = dinv[row] * acc;
}

// ---------------- out[r] = log_softmax(dinv[r]*(V2[r] + sum w*V2[c]) + b2) ----------------
__global__ __launch_bounds__(256) void spmm2_csr(const int* __restrict__ rowstart,
                                                 const int* __restrict__ colbuf,
                                                 const float* __restrict__ wbuf,
                                                 const float* __restrict__ V2,
                                                 const float* __restrict__ dinv,
                                                 const float* __restrict__ b2,
                                                 float* __restrict__ out) {
    int t = threadIdx.x;
    int rr = t >> 4;                  // 16 rows per block
    int j = t & 15;                   // class
    int r = blockIdx.x * 16 + rr;
    int s = rowstart[r], e = rowstart[r + 1];
    float acc = V2[r * NCLASS + j];   // self loop
    for (int k = s; k < e; ++k)
        acc += wbuf[k] * V2[colbuf[k] * NCLASS + j];
    float v = dinv[r] * acc + b2[j];
    // log_softmax across the 16 lanes of this row-group
    float mx = v;
    #pragma unroll
    for (int off = 1; off < 16; off <<= 1) mx = fmaxf(mx, __shfl_xor(mx, off));
    float ex = expf(v - mx);
    float ssum = ex;
    #pragma unroll
    for (int off = 1; off < 16; off <<= 1) ssum += __shfl_xor(ssum, off);
    out[r * NCLASS + j] = v - mx - logf(ssum);
}

extern "C" void kernel_launch(void* const* d_in, const int* in_sizes, int n_in,
                              void* d_out, int out_size, void* d_ws, size_t ws_size,
                              hipStream_t stream) {
    const float* x  = (const float*)d_in[0];
    const int*   ei = (const int*)d_in[1];      // [2, E] flat: row = ei[e], col = ei[E+e]
    const float* ew = (const float*)d_in[2];
    const float* W1 = (const float*)d_in[3];
    const float* b1 = (const float*)d_in[4];
    const float* W2 = (const float*)d_in[5];
    const float* b2 = (const float*)d_in[6];
    float* out = (float*)d_out;

    const int E = N_EDGES;
    const int n = N_NODES;

    // workspace carve-up (bytes). deg/counts/cur contiguous -> one memset.
    // NOTE: rowstart needs N+1 = 8193 ints (32772 B) -> give it 36 KB.
    //       (Round-2 bug: rowstart[8192] aliased colbuf[0].)
    char* ws = (char*)d_ws;
    float* deg      = (float*)(ws);                       // [0, 32K)
    int*   counts   = (int*)  (ws + 32768);               // [32K, 64K)
    int*   cur      = (int*)  (ws + 65536);               // [64K, 96K)
    float* dinv     = (float*)(ws + 98304);               // [96K, 128K)
    int*   rowstart = (int*)  (ws + 131072);              // [128K, 164K) : 8193 ints + pad
    int*   colbuf   = (int*)  (ws + 167936);              // 1 MB
    float* wbuf     = (float*)(ws + 167936 + 1048576);    // 1 MB
    float* V1       = (float*)(ws + 167936 + 2097152);            // 8 MB
    float* H        = (float*)(ws + 167936 + 2097152 + 8388608);  // 8 MB
    float* V2       = (float*)(ws + 167936 + 2097152 + 16777216); // 512 KB

    hipMemsetAsync(ws, 0, 98304, stream);  // deg, counts, cur

    hist_deg_kernel<<<(E + 255) / 256, 256, 0, stream>>>(ei, ew, deg, counts, E);
    dinv_kernel<<<(n + 255) / 256, 256, 0, stream>>>(deg, dinv, n);
    scan_kernel<<<1, 1024, 0, stream>>>(counts, rowstart);
    scatter_kernel<<<(E + 255) / 256, 256, 0, stream>>>(ei, ew, rowstart, cur, colbuf, wbuf, E);

    xw1_kernel<<<n, 256, 0, stream>>>(x, W1, dinv, V1);
    spmm1_csr<<<n, 256, 0, stream>>>(rowstart, colbuf, wbuf, V1, dinv, b1, H);
    hw2_kernel<<<n / 16, 256, 0, stream>>>(H, W2, dinv, V2);
    spmm2_csr<<<n / 16, 256, 0, stream>>>(rowstart, colbuf, wbuf, V2, dinv, b2, out);
}

// Round 4
// 122.186 us; speedup vs baseline: 2.5317x; 1.1507x over previous
//
#include <hip/hip_runtime.h>
#include <math.h>

#define N_NODES 8192
#define N_EDGES 262144
#define NFEAT 128
#define NHID 256
#define NCLASS 16
#define XROWS 16

// ---------------- zero deg + counts (contiguous 64 KB) ----------------
__global__ void zero_kernel(int* __restrict__ p) {
    int i = blockIdx.x * blockDim.x + threadIdx.x;   // 16384 words
    p[i] = 0;
}

// ---------------- histogram + weighted degree ----------------
__global__ void hist_deg_kernel(const int* __restrict__ ei, const float* __restrict__ ew,
                                float* __restrict__ deg, int* __restrict__ counts, int E) {
    int e = blockIdx.x * blockDim.x + threadIdx.x;
    if (e < E) {
        int r = ei[e];
        atomicAdd(&deg[r], ew[e]);
        atomicAdd(&counts[r], 1);
    }
}

// ---------------- exclusive prefix scan of counts + dinv (single block) ----------------
__global__ __launch_bounds__(1024) void scan_kernel(const int* __restrict__ counts,
                                                    const float* __restrict__ deg,
                                                    int* __restrict__ rowstart,
                                                    int* __restrict__ cur,
                                                    float* __restrict__ dinv) {
    __shared__ int wsum[16];
    __shared__ int woff[16];
    int t = threadIdx.x;              // 0..1023, each handles 8 rows
    int base = t * 8;
    int vals[8];
    int s = 0;
    #pragma unroll
    for (int i = 0; i < 8; ++i) {
        vals[i] = s; s += counts[base + i];
        float d = deg[base + i] + 1.0f;            // + self loop, always > 0
        dinv[base + i] = 1.0f / sqrtf(d);
    }
    int lane = t & 63, wave = t >> 6;
    int sc = s;  // inclusive wave scan of per-thread totals
    #pragma unroll
    for (int off = 1; off < 64; off <<= 1) {
        int u = __shfl_up(sc, off);
        if (lane >= off) sc += u;
    }
    if (lane == 63) wsum[wave] = sc;
    __syncthreads();
    if (t == 0) { int acc = 0; for (int i = 0; i < 16; ++i) { woff[i] = acc; acc += wsum[i]; } }
    __syncthreads();
    int texcl = sc - s + woff[wave];
    #pragma unroll
    for (int i = 0; i < 8; ++i) {
        int v = texcl + vals[i];
        rowstart[base + i] = v;
        cur[base + i] = v;            // scatter's running cursor starts at rowstart
    }
    if (t == 1023) rowstart[N_NODES] = texcl + s;  // == E
}

// ---------------- scatter edges into CSR order ----------------
__global__ void scatter_kernel(const int* __restrict__ ei, const float* __restrict__ ew,
                               int* __restrict__ cur,
                               int* __restrict__ colbuf, float* __restrict__ wbuf, int E) {
    int e = blockIdx.x * blockDim.x + threadIdx.x;
    if (e < E) {
        int r = ei[e];
        int pos = atomicAdd(&cur[r], 1);
        colbuf[pos] = ei[E + e];
        wbuf[pos] = ew[e];
    }
}

// ---------------- V1 = dinv * (x @ W1), 16 rows per block ----------------
__global__ __launch_bounds__(256) void xw1_kernel(const float* __restrict__ x,
                                                  const float* __restrict__ W1,
                                                  const float* __restrict__ dinv,
                                                  float* __restrict__ V1) {
    __shared__ float xs[XROWS][NFEAT];    // 8 KB
    int rb = blockIdx.x * XROWS;
    int t = threadIdx.x;                  // output column j
    // stage x rows rb..rb+15: 2048 floats = 512 float4, 256 threads x 2
    const float4* xsrc = (const float4*)(x + (size_t)rb * NFEAT);
    float4* xdst = (float4*)(&xs[0][0]);
    xdst[t] = xsrc[t];
    xdst[t + 256] = xsrc[t + 256];
    __syncthreads();
    float acc[XROWS];
    #pragma unroll
    for (int r = 0; r < XROWS; ++r) acc[r] = 0.0f;
    #pragma unroll 4
    for (int k = 0; k < NFEAT; ++k) {
        float w = W1[k * NHID + t];
        #pragma unroll
        for (int r = 0; r < XROWS; ++r) acc[r] += xs[r][k] * w;
    }
    #pragma unroll
    for (int r = 0; r < XROWS; ++r)
        V1[(size_t)(rb + r) * NHID + t] = dinv[rb + r] * acc[r];
}

// ---------------- H[r] = relu(dinv[r]*(V1[r] + sum_e w*V1[c]) + b1)  (gather) ----------------
__global__ __launch_bounds__(256) void spmm1_csr(const int* __restrict__ rowstart,
                                                 const int* __restrict__ colbuf,
                                                 const float* __restrict__ wbuf,
                                                 const float* __restrict__ V1,
                                                 const float* __restrict__ dinv,
                                                 const float* __restrict__ b1,
                                                 float* __restrict__ H) {
    __shared__ int cS[256];
    __shared__ float wS[256];
    int r = blockIdx.x;
    int j = threadIdx.x;
    int s = rowstart[r], e = rowstart[r + 1];
    float acc = V1[r * NHID + j];  // self loop
    for (int base = s; base < e; base += 256) {
        int k = base + j;
        if (k < e) { cS[j] = colbuf[k]; wS[j] = wbuf[k]; }
        __syncthreads();
        int cnt = min(256, e - base);
        for (int t = 0; t < cnt; ++t)
            acc += wS[t] * V1[cS[t] * NHID + j];
        __syncthreads();
    }
    float v = dinv[r] * acc + b1[j];
    H[r * NHID + j] = v > 0.0f ? v : 0.0f;
}

// ---------------- V2 = dinv * (H @ W2) ----------------
__global__ __launch_bounds__(256) void hw2_kernel(const float* __restrict__ H,
                                                  const float* __restrict__ W2,
                                                  const float* __restrict__ dinv,
                                                  float* __restrict__ V2) {
    __shared__ float w2s[NHID * NCLASS];  // 16 KB
    int t = threadIdx.x;
    #pragma unroll
    for (int i = 0; i < 16; ++i) w2s[i * 256 + t] = W2[i * 256 + t];
    __syncthreads();
    int rr = t >> 4;
    int j = t & 15;
    int row = blockIdx.x * 16 + rr;
    float acc = 0.0f;
    #pragma unroll 8
    for (int k = 0; k < NHID; ++k) acc += H[row * NHID + k] * w2s[k * NCLASS + j];
    V2[row * NCLASS + j] = dinv[row] * acc;
}

// ---------------- out[r] = log_softmax(dinv[r]*(V2[r] + sum w*V2[c]) + b2) ----------------
__global__ __launch_bounds__(256) void spmm2_csr(const int* __restrict__ rowstart,
                                                 const int* __restrict__ colbuf,
                                                 const float* __restrict__ wbuf,
                                                 const float* __restrict__ V2,
                                                 const float* __restrict__ dinv,
                                                 const float* __restrict__ b2,
                                                 float* __restrict__ out) {
    int t = threadIdx.x;
    int rr = t >> 4;                  // 16 rows per block
    int j = t & 15;                   // class
    int r = blockIdx.x * 16 + rr;
    int s = rowstart[r], e = rowstart[r + 1];
    float acc = V2[r * NCLASS + j];   // self loop
    for (int k = s; k < e; ++k)
        acc += wbuf[k] * V2[colbuf[k] * NCLASS + j];
    float v = dinv[r] * acc + b2[j];
    // log_softmax across the 16 lanes of this row-group
    float mx = v;
    #pragma unroll
    for (int off = 1; off < 16; off <<= 1) mx = fmaxf(mx, __shfl_xor(mx, off));
    float ex = expf(v - mx);
    float ssum = ex;
    #pragma unroll
    for (int off = 1; off < 16; off <<= 1) ssum += __shfl_xor(ssum, off);
    out[r * NCLASS + j] = v - mx - logf(ssum);
}

extern "C" void kernel_launch(void* const* d_in, const int* in_sizes, int n_in,
                              void* d_out, int out_size, void* d_ws, size_t ws_size,
                              hipStream_t stream) {
    const float* x  = (const float*)d_in[0];
    const int*   ei = (const int*)d_in[1];      // [2, E] flat: row = ei[e], col = ei[E+e]
    const float* ew = (const float*)d_in[2];
    const float* W1 = (const float*)d_in[3];
    const float* b1 = (const float*)d_in[4];
    const float* W2 = (const float*)d_in[5];
    const float* b2 = (const float*)d_in[6];
    float* out = (float*)d_out;

    const int E = N_EDGES;
    const int n = N_NODES;

    // workspace carve-up (bytes). deg+counts contiguous -> one zero kernel.
    char* ws = (char*)d_ws;
    float* deg      = (float*)(ws);                       // [0, 32K)
    int*   counts   = (int*)  (ws + 32768);               // [32K, 64K)
    int*   cur      = (int*)  (ws + 65536);               // [64K, 96K) (init by scan)
    float* dinv     = (float*)(ws + 98304);               // [96K, 128K)
    int*   rowstart = (int*)  (ws + 131072);              // [128K, 164K) : 8193 ints + pad
    int*   colbuf   = (int*)  (ws + 167936);              // 1 MB
    float* wbuf     = (float*)(ws + 167936 + 1048576);    // 1 MB
    float* V1       = (float*)(ws + 167936 + 2097152);            // 8 MB
    float* H        = (float*)(ws + 167936 + 2097152 + 8388608);  // 8 MB
    float* V2       = (float*)(ws + 167936 + 2097152 + 16777216); // 512 KB

    zero_kernel<<<64, 256, 0, stream>>>((int*)ws);  // deg + counts = 16384 words

    hist_deg_kernel<<<(E + 255) / 256, 256, 0, stream>>>(ei, ew, deg, counts, E);
    scan_kernel<<<1, 1024, 0, stream>>>(counts, deg, rowstart, cur, dinv);
    scatter_kernel<<<(E + 255) / 256, 256, 0, stream>>>(ei, ew, cur, colbuf, wbuf, E);

    xw1_kernel<<<n / XROWS, 256, 0, stream>>>(x, W1, dinv, V1);
    spmm1_csr<<<n, 256, 0, stream>>>(rowstart, colbuf, wbuf, V1, dinv, b1, H);
    hw2_kernel<<<n / 16, 256, 0, stream>>>(H, W2, dinv, V2);
    spmm2_csr<<<n / 16, 256, 0, stream>>>(rowstart, colbuf, wbuf, V2, dinv, b2, out);
}

// Round 5
// 106.035 us; speedup vs baseline: 2.9173x; 1.1523x over previous
//
#include <hip/hip_runtime.h>
#include <math.h>

#define N_NODES 8192
#define N_EDGES 262144
#define NFEAT 128
#define NHID 256
#define NCLASS 16

// ---------------- zero deg + counts (contiguous 64 KB) ----------------
__global__ void zero_kernel(int* __restrict__ p) {
    int i = blockIdx.x * blockDim.x + threadIdx.x;   // 16384 words
    p[i] = 0;
}

// ---------------- histogram + weighted degree ----------------
__global__ void hist_deg_kernel(const int* __restrict__ ei, const float* __restrict__ ew,
                                float* __restrict__ deg, int* __restrict__ counts, int E) {
    int e = blockIdx.x * blockDim.x + threadIdx.x;
    if (e < E) {
        int r = ei[e];
        atomicAdd(&deg[r], ew[e]);
        atomicAdd(&counts[r], 1);
    }
}

// ---------------- exclusive prefix scan of counts + dinv (single block) ----------------
__global__ __launch_bounds__(1024) void scan_kernel(const int* __restrict__ counts,
                                                    const float* __restrict__ deg,
                                                    int* __restrict__ rowstart,
                                                    int* __restrict__ cur,
                                                    float* __restrict__ dinv) {
    __shared__ int wsum[16];
    __shared__ int woff[16];
    int t = threadIdx.x;              // 0..1023, each handles 8 rows
    int base = t * 8;
    int vals[8];
    int s = 0;
    #pragma unroll
    for (int i = 0; i < 8; ++i) {
        vals[i] = s; s += counts[base + i];
        float d = deg[base + i] + 1.0f;            // + self loop, always >= 1
        dinv[base + i] = 1.0f / sqrtf(d);
    }
    int lane = t & 63, wave = t >> 6;
    int sc = s;  // inclusive wave scan of per-thread totals
    #pragma unroll
    for (int off = 1; off < 64; off <<= 1) {
        int u = __shfl_up(sc, off);
        if (lane >= off) sc += u;
    }
    if (lane == 63) wsum[wave] = sc;
    __syncthreads();
    if (t == 0) { int acc = 0; for (int i = 0; i < 16; ++i) { woff[i] = acc; acc += wsum[i]; } }
    __syncthreads();
    int texcl = sc - s + woff[wave];
    #pragma unroll
    for (int i = 0; i < 8; ++i) {
        int v = texcl + vals[i];
        rowstart[base + i] = v;
        cur[base + i] = v;            // scatter's running cursor starts at rowstart
    }
    if (t == 1023) rowstart[N_NODES] = texcl + s;  // == E
}

// ---------------- scatter edges into CSR order, weight pre-normalized ----------------
// w' = w * dinv[r] * dinv[c]; packed with col into one 8B store.
__global__ void scatter_kernel(const int* __restrict__ ei, const float* __restrict__ ew,
                               const float* __restrict__ dinv,
                               int* __restrict__ cur, int2* __restrict__ colw, int E) {
    int e = blockIdx.x * blockDim.x + threadIdx.x;
    if (e < E) {
        int r = ei[e];
        int c = ei[E + e];
        int pos = atomicAdd(&cur[r], 1);
        float w = ew[e] * dinv[r] * dinv[c];
        colw[pos] = make_int2(c, __float_as_int(w));
    }
}

// ---------------- AX[r] = dinv[r]^2 * x[r] + sum_e w' * x[c]   (128-dim gather) ----------------
// 8 rows/block, 32 lanes/row, float4 per lane. Edge (c,w) register-staged 32 at a
// time then __shfl-broadcast: only the x-row load is in the per-iteration chain.
__global__ __launch_bounds__(256) void agg1_kernel(const int* __restrict__ rowstart,
                                                   const int2* __restrict__ colw,
                                                   const float* __restrict__ x,
                                                   const float* __restrict__ dinv,
                                                   float* __restrict__ AX) {
    int t = threadIdx.x;
    int lane = t & 31;                  // float4 index within row (128/4 = 32)
    int r = blockIdx.x * 8 + (t >> 5);
    int s = rowstart[r], e = rowstart[r + 1];
    const float4* x4 = (const float4*)x;
    float di = dinv[r];
    float c0 = di * di;
    float4 xv = x4[r * 32 + lane];
    float4 acc;
    acc.x = c0 * xv.x; acc.y = c0 * xv.y; acc.z = c0 * xv.z; acc.w = c0 * xv.w;
    for (int base = s; base < e; base += 32) {
        int kk = base + lane;
        int2 cw = colw[kk < e ? kk : s];   // lanes past end read a valid dummy
        int m = min(32, e - base);
        for (int u = 0; u < m; ++u) {
            int c = __shfl(cw.x, u, 32);
            float w = __int_as_float(__shfl(cw.y, u, 32));
            float4 v = x4[c * 32 + lane];
            acc.x += w * v.x; acc.y += w * v.y; acc.z += w * v.z; acc.w += w * v.w;
        }
    }
    ((float4*)AX)[r * 32 + lane] = acc;
}

// ---------------- H = relu(AX @ W1 + b1), 16 rows per block ----------------
__global__ __launch_bounds__(256) void gemm1_kernel(const float* __restrict__ AX,
                                                    const float* __restrict__ W1,
                                                    const float* __restrict__ b1,
                                                    float* __restrict__ H) {
    __shared__ float xs[16][NFEAT];       // 8 KB
    int rb = blockIdx.x * 16;
    int t = threadIdx.x;                  // output column j
    const float4* src = (const float4*)(AX + (size_t)rb * NFEAT);
    float4* dst = (float4*)(&xs[0][0]);
    dst[t] = src[t];
    dst[t + 256] = src[t + 256];
    __syncthreads();
    float acc[16];
    #pragma unroll
    for (int r = 0; r < 16; ++r) acc[r] = 0.0f;
    #pragma unroll 4
    for (int k = 0; k < NFEAT; ++k) {
        float w = W1[k * NHID + t];
        #pragma unroll
        for (int r = 0; r < 16; ++r) acc[r] += xs[r][k] * w;
    }
    float bb = b1[t];
    #pragma unroll
    for (int r = 0; r < 16; ++r) {
        float v = acc[r] + bb;
        H[(size_t)(rb + r) * NHID + t] = v > 0.0f ? v : 0.0f;
    }
}

// ---------------- V2 = H @ W2 (no dinv: it's folded into w') ----------------
__global__ __launch_bounds__(256) void gemm2_kernel(const float* __restrict__ H,
                                                    const float* __restrict__ W2,
                                                    float* __restrict__ V2) {
    __shared__ float w2s[NHID * NCLASS];  // 16 KB
    int t = threadIdx.x;
    #pragma unroll
    for (int i = 0; i < 16; ++i) w2s[i * 256 + t] = W2[i * 256 + t];
    __syncthreads();
    int rr = t >> 4;
    int j = t & 15;
    int row = blockIdx.x * 16 + rr;
    float acc = 0.0f;
    #pragma unroll 8
    for (int k = 0; k < NHID; ++k) acc += H[(size_t)row * NHID + k] * w2s[k * NCLASS + j];
    V2[row * NCLASS + j] = acc;
}

// ---------------- out[r] = log_softmax(dinv[r]^2*V2[r] + sum w'*V2[c] + b2) ----------------
__global__ __launch_bounds__(256) void agg2_kernel(const int* __restrict__ rowstart,
                                                   const int2* __restrict__ colw,
                                                   const float* __restrict__ V2,
                                                   const float* __restrict__ dinv,
                                                   const float* __restrict__ b2,
                                                   float* __restrict__ out) {
    int t = threadIdx.x;
    int j = t & 15;                   // class
    int r = blockIdx.x * 16 + (t >> 4);
    int s = rowstart[r], e = rowstart[r + 1];
    float di = dinv[r];
    float acc = di * di * V2[r * NCLASS + j];
    for (int base = s; base < e; base += 16) {
        int kk = base + j;
        int2 cw = colw[kk < e ? kk : s];
        int m = min(16, e - base);
        for (int u = 0; u < m; ++u) {
            int c = __shfl(cw.x, u, 16);
            float w = __int_as_float(__shfl(cw.y, u, 16));
            acc += w * V2[c * NCLASS + j];
        }
    }
    float v = acc + b2[j];
    // log_softmax across the 16 lanes of this row-group
    float mx = v;
    #pragma unroll
    for (int off = 1; off < 16; off <<= 1) mx = fmaxf(mx, __shfl_xor(mx, off));
    float ex = expf(v - mx);
    float ssum = ex;
    #pragma unroll
    for (int off = 1; off < 16; off <<= 1) ssum += __shfl_xor(ssum, off);
    out[r * NCLASS + j] = v - mx - logf(ssum);
}

extern "C" void kernel_launch(void* const* d_in, const int* in_sizes, int n_in,
                              void* d_out, int out_size, void* d_ws, size_t ws_size,
                              hipStream_t stream) {
    const float* x  = (const float*)d_in[0];
    const int*   ei = (const int*)d_in[1];      // [2, E] flat: row = ei[e], col = ei[E+e]
    const float* ew = (const float*)d_in[2];
    const float* W1 = (const float*)d_in[3];
    const float* b1 = (const float*)d_in[4];
    const float* W2 = (const float*)d_in[5];
    const float* b2 = (const float*)d_in[6];
    float* out = (float*)d_out;

    const int E = N_EDGES;
    const int n = N_NODES;

    // workspace carve-up (bytes)
    char* ws = (char*)d_ws;
    float* deg      = (float*)(ws);                       // [0, 32K)
    int*   counts   = (int*)  (ws + 32768);               // [32K, 64K)
    int*   cur      = (int*)  (ws + 65536);               // [64K, 96K) (init by scan)
    float* dinv     = (float*)(ws + 98304);               // [96K, 128K)
    int*   rowstart = (int*)  (ws + 131072);              // [128K, 164K): 8193 ints + pad
    int2*  colw     = (int2*) (ws + 167936);              // 2 MB + slack
    float* AX       = (float*)(ws + 4194304);             // 4 MB
    float* H        = (float*)(ws + 8388608);             // 8 MB
    float* V2       = (float*)(ws + 16777216);            // 512 KB

    zero_kernel<<<64, 256, 0, stream>>>((int*)ws);  // deg + counts = 16384 words

    hist_deg_kernel<<<(E + 255) / 256, 256, 0, stream>>>(ei, ew, deg, counts, E);
    scan_kernel<<<1, 1024, 0, stream>>>(counts, deg, rowstart, cur, dinv);
    scatter_kernel<<<(E + 255) / 256, 256, 0, stream>>>(ei, ew, dinv, cur, colw, E);

    agg1_kernel<<<n / 8, 256, 0, stream>>>(rowstart, colw, x, dinv, AX);
    gemm1_kernel<<<n / 16, 256, 0, stream>>>(AX, W1, b1, H);
    gemm2_kernel<<<n / 16, 256, 0, stream>>>(H, W2, V2);
    agg2_kernel<<<n / 16, 256, 0, stream>>>(rowstart, colw, V2, dinv, b2, out);
}